// Round 1
// baseline (717.453 us; speedup 1.0000x reference)
//
#include <hip/hip_runtime.h>

#define LRELU(v) ((v) > 0.f ? (v) : 0.2f * (v))

// ---------------- CSR construction ----------------
__global__ __launch_bounds__(256) void hist_kernel(const int* __restrict__ dst,
                                                   int* __restrict__ cnt, int E) {
    int e = blockIdx.x * 256 + threadIdx.x;
    if (e < E) atomicAdd(&cnt[dst[e]], 1);
}

__global__ __launch_bounds__(1024) void scan_kernel(const int* __restrict__ cnt,
                                                    int* __restrict__ offv, int N) {
    __shared__ int sh[1024];
    __shared__ int carry;
    int t = threadIdx.x;
    if (t == 0) carry = 0;
    __syncthreads();
    for (int base = 0; base < N; base += 1024) {
        int v = (base + t < N) ? cnt[base + t] : 0;
        sh[t] = v;
        __syncthreads();
        for (int o = 1; o < 1024; o <<= 1) {
            int x = (t >= o) ? sh[t - o] : 0;
            __syncthreads();
            sh[t] += x;
            __syncthreads();
        }
        if (base + t < N) offv[base + t] = carry + sh[t] - v;   // exclusive
        __syncthreads();
        if (t == 0) carry += sh[1023];
        __syncthreads();
    }
    if (t == 0) offv[N] = carry;   // == E
}

__global__ __launch_bounds__(256) void fill_kernel(const int* __restrict__ dst,
                                                   const int* __restrict__ offv,
                                                   int* __restrict__ cur,
                                                   int* __restrict__ csr, int E) {
    int e = blockIdx.x * 256 + threadIdx.x;
    if (e < E) {
        int d = dst[e];
        int p = atomicAdd(&cur[d], 1);
        csr[offv[d] + p] = e;
    }
}

// ---------------- fp32 tiled GEMM: C[M,N] = A[M,K] @ B[K,N] ----------------
// BM=BN=64, TK=16, 256 threads, 4x4 micro-tile. N,K multiples required; M guarded.
__global__ __launch_bounds__(256) void gemm_f32(const float* __restrict__ A,
                                                const float* __restrict__ B,
                                                float* __restrict__ Cm,
                                                int M, int Nn, int K) {
    __shared__ float As[16][68];
    __shared__ float Bs[16][68];
    const int t = threadIdx.x;
    const int tx = t & 15, ty = t >> 4;
    const int m0 = blockIdx.x * 64, n0 = blockIdx.y * 64;
    float acc[4][4] = {};
    for (int k0 = 0; k0 < K; k0 += 16) {
        {   // A tile 64x16 -> As[k][m]
            const int kk = t & 15;
            const int mb = t >> 4;
#pragma unroll
            for (int i = 0; i < 4; ++i) {
                int m = mb + 16 * i;
                int gm = m0 + m;
                float v = (gm < M) ? A[(size_t)gm * K + k0 + kk] : 0.f;
                As[kk][m] = v;
            }
        }
        {   // B tile 16x64 -> Bs[k][n]
            const int nn = t & 63;
            const int k4 = t >> 6;
#pragma unroll
            for (int i = 0; i < 4; ++i) {
                int k = k4 * 4 + i;
                Bs[k][nn] = B[(size_t)(k0 + k) * Nn + n0 + nn];
            }
        }
        __syncthreads();
#pragma unroll
        for (int k = 0; k < 16; ++k) {
            float a[4], b[4];
#pragma unroll
            for (int i = 0; i < 4; ++i) a[i] = As[k][ty * 4 + i];
#pragma unroll
            for (int j = 0; j < 4; ++j) b[j] = Bs[k][tx * 4 + j];
#pragma unroll
            for (int i = 0; i < 4; ++i)
#pragma unroll
                for (int j = 0; j < 4; ++j) acc[i][j] += a[i] * b[j];
        }
        __syncthreads();
    }
#pragma unroll
    for (int i = 0; i < 4; ++i) {
        int gm = m0 + ty * 4 + i;
        if (gm < M) {
#pragma unroll
            for (int j = 0; j < 4; ++j)
                Cm[(size_t)gm * Nn + n0 + tx * 4 + j] = acc[i][j];
        }
    }
}

// ---------------- per-node alpha dots: alpha_s/d[n][h] = h[n,h,:].a[h,:] ----------------
// block = H*64 threads, grid = N. a_s/a_d are flat [H*64].
__global__ void alpha_kernel(const float* __restrict__ h, const float* __restrict__ a_s,
                             const float* __restrict__ a_d, float* __restrict__ als,
                             float* __restrict__ ald, int H) {
    const int n = blockIdx.x;
    const int t = threadIdx.x;
    const int F = H * 64;
    const int hh = t >> 6;
    float v = h[(size_t)n * F + t];
    float s1 = v * a_s[t];
    float s2 = v * a_d[t];
#pragma unroll
    for (int o = 32; o; o >>= 1) {
        s1 += __shfl_xor(s1, o);
        s2 += __shfl_xor(s2, o);
    }
    if ((t & 63) == 0) {
        als[n * H + hh] = s1;
        ald[n * H + hh] = s2;
    }
}

// ---------------- fused segment-softmax + aggregation, one block per dst node ----------------
// ACT: 0 = ELU, 1 = ReLU.  C=64 fixed; block = H*64 threads; wave w == head w.
template <int H, int ACT>
__global__ __launch_bounds__(H * 64) void gat_aggregate(
    const float* __restrict__ hmat, const float* __restrict__ als,
    const float* __restrict__ ald, const int* __restrict__ srcv,
    const int* __restrict__ csr, const int* __restrict__ offv,
    const float* __restrict__ bias, float* __restrict__ outp) {
    constexpr int F = H * 64;
    const int n = blockIdx.x;
    const int t = threadIdx.x;
    const int hh = t >> 6;
    const int lane = t & 63;
    __shared__ int sid[256];
    const int start = offv[n];
    const int deg = offv[n + 1] - start;
    const float adn = ald[n * H + hh];
    const float e_self = LRELU(als[n * H + hh] + adn);
    // pass 1: per-head max (self-loop included)
    float mx = e_self;
    for (int base = 0; base < deg; base += 256) {
        int nb = min(256, deg - base);
        __syncthreads();
        for (int i = t; i < nb; i += F) sid[i] = srcv[csr[start + base + i]];
        __syncthreads();
        for (int i = lane; i < nb; i += 64) {
            float e = LRELU(als[sid[i] * H + hh] + adn);
            mx = fmaxf(mx, e);
        }
    }
#pragma unroll
    for (int o = 32; o; o >>= 1) mx = fmaxf(mx, __shfl_xor(mx, o));
    // pass 2: accumulate numerator and denom (uniform edge walk => every thread has full denom)
    float wself = __expf(e_self - mx);
    float acc = hmat[(size_t)n * F + t] * wself;
    float dsum = wself;
    for (int base = 0; base < deg; base += 256) {
        int nb = min(256, deg - base);
        __syncthreads();
        for (int i = t; i < nb; i += F) sid[i] = srcv[csr[start + base + i]];
        __syncthreads();
        for (int i = 0; i < nb; ++i) {
            int s = sid[i];
            float w = __expf(LRELU(als[s * H + hh] + adn) - mx);
            acc += hmat[(size_t)s * F + t] * w;
            dsum += w;
        }
    }
    float val = acc / (dsum + 1e-16f) + bias[t];
    if (ACT == 0)
        val = (val > 0.f) ? val : (__expf(val) - 1.f);   // ELU
    else
        val = fmaxf(val, 0.f);                           // ReLU
    outp[(size_t)n * F + t] = val;
}

// ---------------- classifier: relu(h3@cW1+cb1)@cW2+cb2 -> log_softmax ----------------
__global__ __launch_bounds__(64) void classifier_kernel(
    const float* __restrict__ h3, const float* __restrict__ cW1,
    const float* __restrict__ cb1, const float* __restrict__ cW2,
    const float* __restrict__ cb2, float* __restrict__ outp) {
    const int n = blockIdx.x;
    const int t = threadIdx.x;
    __shared__ float xs[64];
    __shared__ float hid[32];
    __shared__ float lg[2];
    xs[t] = h3[(size_t)n * 64 + t];
    __syncthreads();
    if (t < 32) {
        float s = cb1[t];
#pragma unroll
        for (int c = 0; c < 64; ++c) s += xs[c] * cW1[c * 32 + t];
        hid[t] = fmaxf(s, 0.f);
    }
    __syncthreads();
    if (t < 2) {
        float s = cb2[t];
#pragma unroll
        for (int j = 0; j < 32; ++j) s += hid[j] * cW2[j * 2 + t];
        lg[t] = s;
    }
    __syncthreads();
    if (t == 0) {
        float a = lg[0], b = lg[1];
        float m = fmaxf(a, b);
        float lse = m + logf(__expf(a - m) + __expf(b - m));
        outp[(size_t)n * 2 + 0] = a - lse;
        outp[(size_t)n * 2 + 1] = b - lse;
    }
}

extern "C" void kernel_launch(void* const* d_in, const int* in_sizes, int n_in,
                              void* d_out, int out_size, void* d_ws, size_t ws_size,
                              hipStream_t stream) {
    const float* x   = (const float*)d_in[0];
    const int*   ei  = (const int*)d_in[1];
    const float* W1  = (const float*)d_in[2];
    const float* a1s = (const float*)d_in[3];
    const float* a1d = (const float*)d_in[4];
    const float* b1  = (const float*)d_in[5];
    const float* W2  = (const float*)d_in[6];
    const float* a2s = (const float*)d_in[7];
    const float* a2d = (const float*)d_in[8];
    const float* b2  = (const float*)d_in[9];
    const float* W3  = (const float*)d_in[10];
    const float* a3s = (const float*)d_in[11];
    const float* a3d = (const float*)d_in[12];
    const float* b3  = (const float*)d_in[13];
    const float* cW1 = (const float*)d_in[14];
    const float* cb1 = (const float*)d_in[15];
    const float* cW2 = (const float*)d_in[16];
    const float* cb2 = (const float*)d_in[17];

    const int N = in_sizes[0] / 128;   // 50000
    const int E = in_sizes[1] / 2;     // 500000
    const int* srcv = ei;
    const int* dstv = ei + E;

    // workspace layout (~107 MB)
    float* buf0 = (float*)d_ws;                       // [N,256]
    float* buf1 = buf0 + (size_t)N * 256;             // [N,256]
    float* als  = buf1 + (size_t)N * 256;             // [N,4]
    float* ald  = als + (size_t)N * 4;                // [N,4]
    int* cnt  = (int*)(ald + (size_t)N * 4);          // [N]
    int* offv = cnt + N;                              // [N+1]
    int* csr  = offv + (N + 1);                       // [E]

    // CSR by destination (rebuilt every call: deterministic work)
    hipMemsetAsync(cnt, 0, (size_t)N * sizeof(int), stream);
    hist_kernel<<<(E + 255) / 256, 256, 0, stream>>>(dstv, cnt, E);
    scan_kernel<<<1, 1024, 0, stream>>>(cnt, offv, N);
    hipMemsetAsync(cnt, 0, (size_t)N * sizeof(int), stream);
    fill_kernel<<<(E + 255) / 256, 256, 0, stream>>>(dstv, offv, cnt, csr, E);

    // ---- layer 1 (F_in=128 -> F=256, H=4, ELU) ----
    gemm_f32<<<dim3((N + 63) / 64, 256 / 64), 256, 0, stream>>>(x, W1, buf0, N, 256, 128);
    alpha_kernel<<<N, 256, 0, stream>>>(buf0, a1s, a1d, als, ald, 4);
    gat_aggregate<4, 0><<<N, 256, 0, stream>>>(buf0, als, ald, srcv, csr, offv, b1, buf1);

    // ---- layer 2 (256 -> 256, H=4, ELU) ----
    gemm_f32<<<dim3((N + 63) / 64, 256 / 64), 256, 0, stream>>>(buf1, W2, buf0, N, 256, 256);
    alpha_kernel<<<N, 256, 0, stream>>>(buf0, a2s, a2d, als, ald, 4);
    gat_aggregate<4, 0><<<N, 256, 0, stream>>>(buf0, als, ald, srcv, csr, offv, b2, buf1);

    // ---- layer 3 (256 -> 64, H=1, ReLU) ----
    gemm_f32<<<dim3((N + 63) / 64, 64 / 64), 256, 0, stream>>>(buf1, W3, buf0, N, 64, 256);
    alpha_kernel<<<N, 64, 0, stream>>>(buf0, a3s, a3d, als, ald, 1);
    gat_aggregate<1, 1><<<N, 64, 0, stream>>>(buf0, als, ald, srcv, csr, offv, b3, buf1);

    // ---- classifier + log_softmax ----
    classifier_kernel<<<N, 64, 0, stream>>>(buf1, cW1, cb1, cW2, cb2, (float*)d_out);
}